// Round 11
// baseline (318.232 us; speedup 1.0000x reference)
//
#include <hip/hip_runtime.h>

#define TT   2048
#define CC   256
#define LL   256
#define SS   513            // 2*LL+1
#define TM   1023           // meet point: fwd -> alpha[TM], bwd -> gamma[TM+1]
#define EPSF (1e-7f)
#define LN2F (0.69314718055994531f)
#define DPTH 8              // register prefetch depth (fallback kernel)
#define RBTH 64             // rebase threshold (bits)
#define NCH  127            // fallback: 127*8 + 7 = 1023 steps
#define EMINI (-2000000000)
#define GL   256            // compact gat row: 256 label probs (1 KB)

#if __has_builtin(__builtin_amdgcn_frexp_expf)
#define FREXP_EXP __builtin_amdgcn_frexp_expf
#else
static __device__ __forceinline__ int FREXP_EXP(float x){ int e; return (frexpf(x,&e), e); }
#endif
#if __has_builtin(__builtin_amdgcn_ldexpf)
#define LDEXP __builtin_amdgcn_ldexpf
#else
#define LDEXP ldexpf
#endif

// async stage: 64 lanes x 16B = one 1KB chunk -> LDS (lane-linear dest)
__device__ __forceinline__ void stage16(const float* g, float* l)
{
    __builtin_amdgcn_global_load_lds(
        (const __attribute__((address_space(1))) unsigned int*)g,
        (__attribute__((address_space(3))) unsigned int*)l,
        16, 0, 0);
}

#define VMWAIT(N) do {                                        \
        asm volatile("s_waitcnt vmcnt(" #N ")" ::: "memory"); \
        __builtin_amdgcn_sched_barrier(0);                    \
    } while (0)

// ---------------------------------------------------------------------------
// Pass 1: compact gather.
//   gatL[b][t][i]  = y_pred[b][t][lab[i]] + eps   (i = 0..255, 1KB rows)
//   blankA[b][t]   = y_pred[b][t][blank]  + eps
// ---------------------------------------------------------------------------
__launch_bounds__(256, 4)
__global__ void ctc_gather_kernel(const int* __restrict__ y_true,
                                  const float* __restrict__ y_pred,
                                  float* __restrict__ gatL,
                                  float* __restrict__ blankA)
{
    const int b   = blockIdx.x;
    const int i   = threadIdx.x;                 // 0..255
    const int col = y_true[b * LL + i];
    const float* rp = y_pred + (size_t)b * TT * CC;
    float*       gp = gatL   + (size_t)b * TT * GL;
    float*       bp = blankA + (size_t)b * TT;
    const int tch = TT / gridDim.y;
    const int t0  = blockIdx.y * tch;
    #pragma unroll 4
    for (int t = t0; t < t0 + tch; ++t) {
        gp[(size_t)t * GL + i] = rp[(size_t)t * CC + col] + EPSF;
        if (i == 255)
            bp[t] = rp[(size_t)t * CC + (CC - 1)] + EPSF;
    }
}

// ---------------------------------------------------------------------------
// Pass 2: meet-in-the-middle DP. Block = 128 threads (2 waves) per batch.
//   wave 0: forward alpha DP, rows 1..TM       (init row 0)
//   wave 1: backward gamma DP, rows TT-2..TM+1 (init row TT-1)
// Lane l owns cells s = 8l..8l+7 + shadow f[8]. Rows staged into a per-wave
// 8-slot LDS ring via ONE global_load_lds each (1KB, lane-linear); consumed
// as one conflict-free ds_read_b128 (own 4 label probs) + one broadcast
// ds_read_b32 (blank, from an LDS table staged once). Counted vmcnt(6);
// pv read one step ahead. Extended-range floats: value = f[j]*2^e.
// ---------------------------------------------------------------------------
__launch_bounds__(128, 1)
__global__ void ctc_fast_kernel(const int* __restrict__ y_true,
                                const float* __restrict__ y_pred,
                                const float* __restrict__ gatL,
                                const float* __restrict__ blankA,
                                float* __restrict__ out)
{
    __shared__ __align__(16) float ring[2][8][GL];   // 16 KB
    __shared__ __align__(16) float blk[2][TT];       // 16 KB (blank table/wave)
    __shared__ float cw[SS];   // beta[TM][s] combo mantissas (per-lane scale)
    __shared__ int   ew[64];   // bwd per-lane exponent

    const int tid   = threadIdx.x;
    const int w     = tid >> 6;          // 0 = fwd, 1 = bwd (wave-uniform)
    const int lane  = tid & 63;
    const int b     = blockIdx.x;
    const int blank = CC - 1;

    const int*   lab   = y_true + b * LL;
    const float* base  = y_pred + (size_t)b * TT * CC;
    const float* gLb   = gatL   + (size_t)b * TT * GL;
    const float* bAb   = blankA + (size_t)b * TT;

    float kup[4];    // fwd: allow2 into cell s
    float kdn[4];    // bwd: allow2 out of cell s (into s+2)
    const int col0 = lab[4 * lane];
    #pragma unroll
    for (int i = 0; i < 4; ++i) {
        const int li = 4 * lane + i;               // 0..255
        const int z  = lab[li];
        const int zm = (li >= 1) ? lab[li - 1] : -1;
        kup[i] = (z != zm) ? 1.0f : 0.0f;
        kdn[i] = (li <= 254 && lab[li + 1] != z) ? 1.0f : 0.0f;
    }

    float f[9];
    #pragma unroll
    for (int j = 0; j < 9; ++j) f[j] = 0.0f;
    int  e = 0;
    bool lzero;

    if (w == 0) {
        if (lane == 0) {
            f[0] = base[blank] + EPSF;             // s=0, t=0
            f[1] = base[col0]  + EPSF;             // s=1, t=0
        }
        lzero = (lane != 0);
    } else {
        if (lane == 63) {
            const float* rT = base + (size_t)(TT - 1) * CC;
            f[7] = rT[lab[255]] + EPSF;            // s=511, t=TT-1
            f[8] = rT[blank]    + EPSF;            // s=512 (shadow), t=TT-1
        }
        lzero = (lane != 63);
    }

    auto renorm = [&]() {
        float m = fmaxf(fmaxf(fmaxf(f[0], f[1]), fmaxf(f[2], f[3])),
                        fmaxf(fmaxf(f[4], f[5]), fmaxf(f[6], fmaxf(f[7], f[8]))));
        const int em = FREXP_EXP(m);               // frexp_exp(0) == 0
        #pragma unroll
        for (int j = 0; j < 9; ++j) f[j] = LDEXP(f[j], -em);
        e += em;
    };

    auto fwd_step = [&](float pb, float p0, float p1, float p2, float p3) {
        float u7 = __shfl_up(f[7], 1);
        int   ue = __shfl_up(e, 1);
        if (lane == 0) { u7 = 0.0f; ue = e; }
        int dlt = ue - e;
        const bool rb = lzero || (dlt >= RBTH);
        if (__ballot(rb)) {                        // rare: front / scale jump
            const int sh = rb ? -dlt : 0;
            #pragma unroll
            for (int j = 0; j < 9; ++j) f[j] = LDEXP(f[j], sh);
            e   = rb ? ue : e;
            dlt = rb ? 0  : dlt;
            lzero = lzero && (u7 == 0.0f);
        }
        const float bf = LDEXP(u7, dlt);
        const float n0 = (f[0] + bf) * pb;
        const float n1 = (f[1] + f[0] + bf   * kup[0]) * p0;
        const float n2 = (f[2] + f[1]) * pb;
        const float n3 = (f[3] + f[2] + f[1] * kup[1]) * p1;
        const float n4 = (f[4] + f[3]) * pb;
        const float n5 = (f[5] + f[4] + f[3] * kup[2]) * p2;
        const float n6 = (f[6] + f[5]) * pb;
        const float n7 = (f[7] + f[6] + f[5] * kup[3]) * p3;
        const float n8 = (f[8] + f[7]) * pb;
        f[0]=n0; f[1]=n1; f[2]=n2; f[3]=n3; f[4]=n4;
        f[5]=n5; f[6]=n6; f[7]=n7; f[8]=n8;
    };

    auto bwd_step = [&](float pb, float p0, float p1, float p2, float p3) {
        float d1 = __shfl_down(f[1], 1);
        int   de = __shfl_down(e, 1);
        if (lane == 63) { d1 = 0.0f; de = e; }
        int dlt = de - e;
        const bool rb = lzero || (dlt >= RBTH);
        if (__ballot(rb)) {
            const int sh = rb ? -dlt : 0;
            #pragma unroll
            for (int j = 0; j < 9; ++j) f[j] = LDEXP(f[j], sh);
            e   = rb ? de : e;
            dlt = rb ? 0  : dlt;
            lzero = lzero && (d1 == 0.0f);
        }
        const float bf = LDEXP(d1, dlt);
        const float n0 = (f[0] + f[1]) * pb;
        const float n1 = (f[1] + f[2] + f[3] * kdn[0]) * p0;
        const float n2 = (f[2] + f[3]) * pb;
        const float n3 = (f[3] + f[4] + f[5] * kdn[1]) * p1;
        const float n4 = (f[4] + f[5]) * pb;
        const float n5 = (f[5] + f[6] + f[7] * kdn[2]) * p2;
        const float n6 = (f[6] + f[7]) * pb;
        const float n7 = (f[7] + f[8] + bf   * kdn[3]) * p3;
        const float n8 = (f[8] + bf) * pb;
        f[0]=n0; f[1]=n1; f[2]=n2; f[3]=n3; f[4]=n4;
        f[5]=n5; f[6]=n6; f[7]=n7; f[8]=n8;
    };

    // ---- prologue: stage blank table (8 chunks) + first 8 ring rows ----
    {
        const float* bsrc = bAb + 4 * lane;
        #pragma unroll
        for (int ch = 0; ch < 8; ++ch)
            stage16(bsrc + ch * 256, &blk[w][ch * 256]);
        #pragma unroll
        for (int k = 0; k < 8; ++k) {
            const int r = w ? (2046 - k) : (1 + k);   // row(k)
            stage16(gLb + (size_t)r * GL + 4 * lane, &ring[w][k][0]);
        }
    }
    VMWAIT(7);               // 8 blank chunks + ring slot 0 complete
    float4 nx4 = *(const float4*)&ring[w][0][4 * lane];
    float  nxb = blk[w][w ? 2046 : 1];

    // ---- main DP: 1023 steps, LDS ring, counted vmcnt ----
    if (w == 0) {
        const float* gs = gLb + (size_t)9 * GL + 4 * lane;   // row(8) = 9
        int rowN = 2;                                        // row(i+1)
        for (int i = 0; i < 1023; ++i) {
            const float4 c4 = nx4; const float cb = nxb;
            fwd_step(cb, c4.x, c4.y, c4.z, c4.w);
            if ((i & 3) == 3) renorm();
            if (i <= 1014) { VMWAIT(6); } else { VMWAIT(0); }
            if (i < 1022) {
                nx4 = *(const float4*)&ring[0][(i + 1) & 7][4 * lane];
                nxb = blk[0][rowN];
                ++rowN;
            }
            if (i <= 1014) {
                stage16(gs, &ring[0][i & 7][0]);
                gs += GL;
            }
        }
    } else {
        const float* gs = gLb + (size_t)2038 * GL + 4 * lane; // row(8) = 2038
        int rowN = 2045;                                      // row(i+1)
        for (int i = 0; i < 1023; ++i) {
            const float4 c4 = nx4; const float cb = nxb;
            bwd_step(cb, c4.x, c4.y, c4.z, c4.w);
            if ((i & 3) == 3) renorm();
            if (i <= 1014) { VMWAIT(6); } else { VMWAIT(0); }
            if (i < 1022) {
                nx4 = *(const float4*)&ring[1][(i + 1) & 7][4 * lane];
                nxb = blk[1][rowN];
                --rowN;
            }
            if (i <= 1014) {
                stage16(gs, &ring[1][i & 7][0]);
                gs -= GL;
            }
        }

        // combo: beta[TM][s] = g[s] + g[s+1] + allow2[s+2]*g[s+2] (no p mult)
        float d1 = __shfl_down(f[1], 1);
        int   de = __shfl_down(e, 1);
        if (lane == 63) { d1 = 0.0f; de = e; }
        int dlt = de - e;
        if (dlt >= RBTH) {                         // one-shot, per-lane safe
            #pragma unroll
            for (int j = 0; j < 9; ++j) f[j] = LDEXP(f[j], -dlt);
            e = de; dlt = 0;
        }
        const float bf = LDEXP(d1, dlt);
        float cb[9];
        cb[0] = f[0] + f[1];
        cb[1] = f[1] + f[2] + f[3] * kdn[0];
        cb[2] = f[2] + f[3];
        cb[3] = f[3] + f[4] + f[5] * kdn[1];
        cb[4] = f[4] + f[5];
        cb[5] = f[5] + f[6] + f[7] * kdn[2];
        cb[6] = f[6] + f[7];
        cb[7] = f[7] + f[8] + bf   * kdn[3];
        cb[8] = f[8] + bf;                          // combo[512] (lane 63: bf=0)

        #pragma unroll
        for (int j = 0; j < 8; ++j) cw[8 * lane + j] = cb[j];
        if (lane == 63) cw[512] = cb[8];
        ew[lane] = e;
    }

    __syncthreads();

    if (w == 0) {
        // lane l's 8 cells align exactly with bwd lane l's 8 cells
        float part = 0.0f;
        #pragma unroll
        for (int j = 0; j < 8; ++j) part += f[j] * cw[8 * lane + j];
        if (lane == 63) part += f[8] * cw[512];
        int   ep = (part > 0.0f) ? (e + ew[lane]) : EMINI;
        float m  = part;
        #pragma unroll
        for (int d = 1; d < 64; d <<= 1) {
            const float mo = __shfl_xor(m, d);
            const int   eo = __shfl_xor(ep, d);
            const int   E  = ep > eo ? ep : eo;
            m  = LDEXP(m, ep - E) + LDEXP(mo, eo - E);
            ep = E;
        }
        if (lane == 0)
            out[b] = -LN2F * ((float)ep + __builtin_amdgcn_logf(m));
    }
}

// ---------------------------------------------------------------------------
// Fallback (round-6 verbatim, proven): used only if ws_size is too small.
// ---------------------------------------------------------------------------
__launch_bounds__(128, 1)
__global__ void ctc_fb_kernel(const int* __restrict__ y_true,
                              const float* __restrict__ y_pred,
                              float* __restrict__ out)
{
    __shared__ float cw[SS];
    __shared__ int   ew[64];

    const int tid   = threadIdx.x;
    const int w     = tid >> 6;
    const int lane  = tid & 63;
    const int b     = blockIdx.x;
    const int blank = CC - 1;

    const int*   lab  = y_true + b * LL;
    const float* base = y_pred + (size_t)b * TT * CC;

    int   col[4];
    float kup[4], kdn[4];
    #pragma unroll
    for (int i = 0; i < 4; ++i) {
        const int li = 4 * lane + i;
        const int z  = lab[li];
        col[i] = z;
        const int zm = (li >= 1) ? lab[li - 1] : -1;
        kup[i] = (z != zm) ? 1.0f : 0.0f;
        kdn[i] = (li <= 254 && lab[li + 1] != z) ? 1.0f : 0.0f;
    }

    float f[9];
    #pragma unroll
    for (int j = 0; j < 9; ++j) f[j] = 0.0f;
    int  e = 0;
    bool lzero;

    if (w == 0) {
        if (lane == 0) { f[0] = base[blank] + EPSF; f[1] = base[col[0]] + EPSF; }
        lzero = (lane != 0);
    } else {
        if (lane == 63) {
            const float* rT = base + (size_t)(TT - 1) * CC;
            f[7] = rT[col[3]] + EPSF; f[8] = rT[blank] + EPSF;
        }
        lzero = (lane != 63);
    }

    float pfb[DPTH]; float pfl[DPTH][4];
    #pragma unroll
    for (int k = 0; k < DPTH; ++k) {
        const int r = (w == 0) ? (1 + k) : (TT - 2 - k);
        const float* rp = base + (size_t)r * CC;
        pfb[k] = rp[blank];
        #pragma unroll
        for (int i = 0; i < 4; ++i) pfl[k][i] = rp[col[i]];
    }

    auto renorm = [&]() {
        float m = fmaxf(fmaxf(fmaxf(f[0], f[1]), fmaxf(f[2], f[3])),
                        fmaxf(fmaxf(f[4], f[5]), fmaxf(f[6], fmaxf(f[7], f[8]))));
        const int em = FREXP_EXP(m);
        #pragma unroll
        for (int j = 0; j < 9; ++j) f[j] = LDEXP(f[j], -em);
        e += em;
    };
    auto fwd_step = [&](float pb, float p0, float p1, float p2, float p3) {
        float u7 = __shfl_up(f[7], 1);
        int   ue = __shfl_up(e, 1);
        if (lane == 0) { u7 = 0.0f; ue = e; }
        int dlt = ue - e;
        const bool rb = lzero || (dlt >= RBTH);
        if (__ballot(rb)) {
            const int sh = rb ? -dlt : 0;
            #pragma unroll
            for (int j = 0; j < 9; ++j) f[j] = LDEXP(f[j], sh);
            e = rb ? ue : e; dlt = rb ? 0 : dlt;
            lzero = lzero && (u7 == 0.0f);
        }
        const float bf = LDEXP(u7, dlt);
        const float n0 = (f[0] + bf) * pb;
        const float n1 = (f[1] + f[0] + bf   * kup[0]) * p0;
        const float n2 = (f[2] + f[1]) * pb;
        const float n3 = (f[3] + f[2] + f[1] * kup[1]) * p1;
        const float n4 = (f[4] + f[3]) * pb;
        const float n5 = (f[5] + f[4] + f[3] * kup[2]) * p2;
        const float n6 = (f[6] + f[5]) * pb;
        const float n7 = (f[7] + f[6] + f[5] * kup[3]) * p3;
        const float n8 = (f[8] + f[7]) * pb;
        f[0]=n0; f[1]=n1; f[2]=n2; f[3]=n3; f[4]=n4;
        f[5]=n5; f[6]=n6; f[7]=n7; f[8]=n8;
    };
    auto bwd_step = [&](float pb, float p0, float p1, float p2, float p3) {
        float d1 = __shfl_down(f[1], 1);
        int   de = __shfl_down(e, 1);
        if (lane == 63) { d1 = 0.0f; de = e; }
        int dlt = de - e;
        const bool rb = lzero || (dlt >= RBTH);
        if (__ballot(rb)) {
            const int sh = rb ? -dlt : 0;
            #pragma unroll
            for (int j = 0; j < 9; ++j) f[j] = LDEXP(f[j], sh);
            e = rb ? de : e; dlt = rb ? 0 : dlt;
            lzero = lzero && (d1 == 0.0f);
        }
        const float bf = LDEXP(d1, dlt);
        const float n0 = (f[0] + f[1]) * pb;
        const float n1 = (f[1] + f[2] + f[3] * kdn[0]) * p0;
        const float n2 = (f[2] + f[3]) * pb;
        const float n3 = (f[3] + f[4] + f[5] * kdn[1]) * p1;
        const float n4 = (f[4] + f[5]) * pb;
        const float n5 = (f[5] + f[6] + f[7] * kdn[2]) * p2;
        const float n6 = (f[6] + f[7]) * pb;
        const float n7 = (f[7] + f[8] + bf   * kdn[3]) * p3;
        const float n8 = (f[8] + bf) * pb;
        f[0]=n0; f[1]=n1; f[2]=n2; f[3]=n3; f[4]=n4;
        f[5]=n5; f[6]=n6; f[7]=n7; f[8]=n8;
    };

    if (w == 0) {
        for (int c = 0; c < NCH; ++c) {
            #pragma unroll
            for (int k = 0; k < DPTH; ++k) {
                const float pb = pfb[k] + EPSF;
                const float p0 = pfl[k][0] + EPSF, p1 = pfl[k][1] + EPSF;
                const float p2 = pfl[k][2] + EPSF, p3 = pfl[k][3] + EPSF;
                int tp = 1 + c * DPTH + k + DPTH; if (tp > TM) tp = TM;
                const float* rp = base + (size_t)tp * CC;
                pfb[k] = rp[blank];
                #pragma unroll
                for (int i = 0; i < 4; ++i) pfl[k][i] = rp[col[i]];
                fwd_step(pb, p0, p1, p2, p3);
                if (k == 3 || k == 7) renorm();
            }
        }
        #pragma unroll
        for (int k = 0; k < 7; ++k) {
            fwd_step(pfb[k] + EPSF, pfl[k][0] + EPSF, pfl[k][1] + EPSF,
                     pfl[k][2] + EPSF, pfl[k][3] + EPSF);
            if (k == 3) renorm();
        }
    } else {
        for (int c = 0; c < NCH; ++c) {
            #pragma unroll
            for (int k = 0; k < DPTH; ++k) {
                const float pb = pfb[k] + EPSF;
                const float p0 = pfl[k][0] + EPSF, p1 = pfl[k][1] + EPSF;
                const float p2 = pfl[k][2] + EPSF, p3 = pfl[k][3] + EPSF;
                int tp = (TT - 2) - (c * DPTH + k) - DPTH; if (tp < TM + 1) tp = TM + 1;
                const float* rp = base + (size_t)tp * CC;
                pfb[k] = rp[blank];
                #pragma unroll
                for (int i = 0; i < 4; ++i) pfl[k][i] = rp[col[i]];
                bwd_step(pb, p0, p1, p2, p3);
                if (k == 3 || k == 7) renorm();
            }
        }
        #pragma unroll
        for (int k = 0; k < 7; ++k) {
            bwd_step(pfb[k] + EPSF, pfl[k][0] + EPSF, pfl[k][1] + EPSF,
                     pfl[k][2] + EPSF, pfl[k][3] + EPSF);
            if (k == 3) renorm();
        }

        float d1 = __shfl_down(f[1], 1);
        int   de = __shfl_down(e, 1);
        if (lane == 63) { d1 = 0.0f; de = e; }
        int dlt = de - e;
        if (dlt >= RBTH) {
            #pragma unroll
            for (int j = 0; j < 9; ++j) f[j] = LDEXP(f[j], -dlt);
            e = de; dlt = 0;
        }
        const float bf = LDEXP(d1, dlt);
        float cb[9];
        cb[0] = f[0] + f[1];
        cb[1] = f[1] + f[2] + f[3] * kdn[0];
        cb[2] = f[2] + f[3];
        cb[3] = f[3] + f[4] + f[5] * kdn[1];
        cb[4] = f[4] + f[5];
        cb[5] = f[5] + f[6] + f[7] * kdn[2];
        cb[6] = f[6] + f[7];
        cb[7] = f[7] + f[8] + bf   * kdn[3];
        cb[8] = f[8] + bf;
        #pragma unroll
        for (int j = 0; j < 8; ++j) cw[8 * lane + j] = cb[j];
        if (lane == 63) cw[512] = cb[8];
        ew[lane] = e;
    }

    __syncthreads();

    if (w == 0) {
        float part = 0.0f;
        #pragma unroll
        for (int j = 0; j < 8; ++j) part += f[j] * cw[8 * lane + j];
        if (lane == 63) part += f[8] * cw[512];
        int   ep = (part > 0.0f) ? (e + ew[lane]) : EMINI;
        float m  = part;
        #pragma unroll
        for (int d = 1; d < 64; d <<= 1) {
            const float mo = __shfl_xor(m, d);
            const int   eo = __shfl_xor(ep, d);
            const int   E  = ep > eo ? ep : eo;
            m  = LDEXP(m, ep - E) + LDEXP(mo, eo - E);
            ep = E;
        }
        if (lane == 0)
            out[b] = -LN2F * ((float)ep + __builtin_amdgcn_logf(m));
    }
}

extern "C" void kernel_launch(void* const* d_in, const int* in_sizes, int n_in,
                              void* d_out, int out_size, void* d_ws, size_t ws_size,
                              hipStream_t stream)
{
    const int*   y_true = (const int*)d_in[0];
    const float* y_pred = (const float*)d_in[1];
    float*       out    = (float*)d_out;
    const int B = in_sizes[0] / LL;   // 32

    const size_t gatl_elems = (size_t)B * TT * GL;
    const size_t need = (gatl_elems + (size_t)B * TT) * sizeof(float);  // ~64.3 MB
    if (ws_size >= need) {
        float* gatL   = (float*)d_ws;
        float* blankA = gatL + gatl_elems;
        ctc_gather_kernel<<<dim3(B, 32), 256, 0, stream>>>(y_true, y_pred, gatL, blankA);
        ctc_fast_kernel<<<B, 128, 0, stream>>>(y_true, y_pred, gatL, blankA, out);
    } else {
        ctc_fb_kernel<<<B, 128, 0, stream>>>(y_true, y_pred, out);
    }
}

// Round 12
// 211.149 us; speedup vs baseline: 1.5071x; 1.5071x over previous
//
#include <hip/hip_runtime.h>

#define TT   2048
#define CC   256
#define LL   256
#define SS   513            // 2*LL+1
#define TM   1023           // meet point: fwd -> alpha[TM], bwd -> gamma[TM+1]
#define EPSF (1e-7f)
#define LN2F (0.69314718055994531f)
#define DPTH 8              // prefetch depth (steps ahead)
#define RBTH 64             // rebase threshold (bits)
#define NCH  127            // 127*8 + 7 = 1023 steps
#define EMINI (-2000000000)
#define GSTR 260            // gat row stride: 256 labels + 4x blank replicas

#if __has_builtin(__builtin_amdgcn_frexp_expf)
#define FREXP_EXP __builtin_amdgcn_frexp_expf
#else
static __device__ __forceinline__ int FREXP_EXP(float x){ int e; return (frexpf(x,&e), e); }
#endif
#if __has_builtin(__builtin_amdgcn_ldexpf)
#define LDEXP __builtin_amdgcn_ldexpf
#else
#define LDEXP ldexpf
#endif

// ---------------------------------------------------------------------------
// Pass 1: compact gather.
//   gat[b][t][i]        = y_pred[b][t][lab[i]] + eps   (i = 0..255)
//   gat[b][t][256+j]    = y_pred[b][t][blank]  + eps   (j = 0..3, replicas)
// ---------------------------------------------------------------------------
__launch_bounds__(256, 4)
__global__ void ctc_gather_kernel(const int* __restrict__ y_true,
                                  const float* __restrict__ y_pred,
                                  float* __restrict__ gat)
{
    const int b   = blockIdx.x;
    const int i   = threadIdx.x;                 // 0..255
    const int col = y_true[b * LL + i];
    const float* rp = y_pred + (size_t)b * TT * CC;
    float*       gp = gat    + (size_t)b * TT * GSTR;
    const int tch = TT / gridDim.y;
    const int t0  = blockIdx.y * tch;
    #pragma unroll 4
    for (int t = t0; t < t0 + tch; ++t) {
        gp[(size_t)t * GSTR + i] = rp[(size_t)t * CC + col] + EPSF;
        if (i < 4)
            gp[(size_t)t * GSTR + 256 + i] = rp[(size_t)t * CC + (CC - 1)] + EPSF;
    }
}

// ---------------------------------------------------------------------------
// Pass 2: meet-in-the-middle DP. Block = 128 threads (2 waves) per batch.
//   wave 0: forward alpha DP, rows 1..TM       (init row 0)
//   wave 1: backward gamma DP, rows TT-2..TM+1 (init row TT-1)
// Lane l owns cells s = 8l..8l+7 + shadow f[8]. Per step: one float4 global
// load (own 4 label probs) + one divergent-address blank load (col 256+
// (lane&3) -> forced VMEM), prefetched DPTH=8 deep; sched_barrier(0) pins the
// loads at body top so the compiler cannot collapse the pipeline. The main
// loop's lgkm domain contains ONLY the 2 shfls. Branchless per-lane rebase.
// ---------------------------------------------------------------------------
__launch_bounds__(128, 1)
__global__ void ctc_fast_kernel(const int* __restrict__ y_true,
                                const float* __restrict__ y_pred,
                                const float* __restrict__ gat,
                                float* __restrict__ out)
{
    __shared__ float cw[SS];   // beta[TM][s] combo mantissas (per-lane scale)
    __shared__ int   ew[64];   // bwd per-lane exponent

    const int tid   = threadIdx.x;
    const int w     = tid >> 6;          // 0 = fwd, 1 = bwd (wave-uniform)
    const int lane  = tid & 63;
    const int b     = blockIdx.x;
    const int blank = CC - 1;

    const int*   lab   = y_true + b * LL;
    const float* base  = y_pred + (size_t)b * TT * CC;
    const float* gLb   = gat    + (size_t)b * TT * GSTR;

    float kup[4];    // fwd: allow2 into cell s
    float kdn[4];    // bwd: allow2 out of cell s (into s+2)
    const int col0 = lab[4 * lane];
    #pragma unroll
    for (int i = 0; i < 4; ++i) {
        const int li = 4 * lane + i;               // 0..255
        const int z  = lab[li];
        const int zm = (li >= 1) ? lab[li - 1] : -1;
        kup[i] = (z != zm) ? 1.0f : 0.0f;
        kdn[i] = (li <= 254 && lab[li + 1] != z) ? 1.0f : 0.0f;
    }

    float f[9];
    #pragma unroll
    for (int j = 0; j < 9; ++j) f[j] = 0.0f;
    int  e = 0;
    bool lzero;

    if (w == 0) {
        if (lane == 0) {
            f[0] = base[blank] + EPSF;             // s=0, t=0
            f[1] = base[col0]  + EPSF;             // s=1, t=0
        }
        lzero = (lane != 0);
    } else {
        if (lane == 63) {
            const float* rT = base + (size_t)(TT - 1) * CC;
            f[7] = rT[lab[255]] + EPSF;            // s=511, t=TT-1
            f[8] = rT[blank]    + EPSF;            // s=512 (shadow), t=TT-1
        }
        lzero = (lane != 63);
    }

    auto renorm = [&]() {
        float m = fmaxf(fmaxf(fmaxf(f[0], f[1]), fmaxf(f[2], f[3])),
                        fmaxf(fmaxf(f[4], f[5]), fmaxf(f[6], fmaxf(f[7], f[8]))));
        const int em = FREXP_EXP(m);               // frexp_exp(0) == 0
        #pragma unroll
        for (int j = 0; j < 9; ++j) f[j] = LDEXP(f[j], -em);
        e += em;
    };

    // branchless per-lane step (no ballot): identical per-lane semantics to
    // the proven R6/R9 path (ldexp(f,0)=f covers the rb-false case).
    auto fwd_step = [&](float pb, float p0, float p1, float p2, float p3) {
        float u7 = __shfl_up(f[7], 1);
        int   ue = __shfl_up(e, 1);
        if (lane == 0) { u7 = 0.0f; ue = e; }
        const int  dlt = ue - e;
        const bool rb  = lzero || (dlt >= RBTH);
        const int  sh  = rb ? -dlt : 0;
        #pragma unroll
        for (int j = 0; j < 9; ++j) f[j] = LDEXP(f[j], sh);
        e = rb ? ue : e;
        const int dlt2 = rb ? 0 : dlt;
        lzero = lzero && (u7 == 0.0f);
        const float bf = LDEXP(u7, dlt2);
        const float n0 = (f[0] + bf) * pb;
        const float n1 = (f[1] + f[0] + bf   * kup[0]) * p0;
        const float n2 = (f[2] + f[1]) * pb;
        const float n3 = (f[3] + f[2] + f[1] * kup[1]) * p1;
        const float n4 = (f[4] + f[3]) * pb;
        const float n5 = (f[5] + f[4] + f[3] * kup[2]) * p2;
        const float n6 = (f[6] + f[5]) * pb;
        const float n7 = (f[7] + f[6] + f[5] * kup[3]) * p3;
        const float n8 = (f[8] + f[7]) * pb;
        f[0]=n0; f[1]=n1; f[2]=n2; f[3]=n3; f[4]=n4;
        f[5]=n5; f[6]=n6; f[7]=n7; f[8]=n8;
    };

    auto bwd_step = [&](float pb, float p0, float p1, float p2, float p3) {
        float d1 = __shfl_down(f[1], 1);
        int   de = __shfl_down(e, 1);
        if (lane == 63) { d1 = 0.0f; de = e; }
        const int  dlt = de - e;
        const bool rb  = lzero || (dlt >= RBTH);
        const int  sh  = rb ? -dlt : 0;
        #pragma unroll
        for (int j = 0; j < 9; ++j) f[j] = LDEXP(f[j], sh);
        e = rb ? de : e;
        const int dlt2 = rb ? 0 : dlt;
        lzero = lzero && (d1 == 0.0f);
        const float bf = LDEXP(d1, dlt2);
        const float n0 = (f[0] + f[1]) * pb;
        const float n1 = (f[1] + f[2] + f[3] * kdn[0]) * p0;
        const float n2 = (f[2] + f[3]) * pb;
        const float n3 = (f[3] + f[4] + f[5] * kdn[1]) * p1;
        const float n4 = (f[4] + f[5]) * pb;
        const float n5 = (f[5] + f[6] + f[7] * kdn[2]) * p2;
        const float n6 = (f[6] + f[7]) * pb;
        const float n7 = (f[7] + f[8] + bf   * kdn[3]) * p3;
        const float n8 = (f[8] + bf) * pb;
        f[0]=n0; f[1]=n1; f[2]=n2; f[3]=n3; f[4]=n4;
        f[5]=n5; f[6]=n6; f[7]=n7; f[8]=n8;
    };

    // ---- prefetch ring (registers), DPTH=8 rows ahead ----
    float4 pf[DPTH];
    float  pbf[DPTH];
    const int bofs = 256 + (lane & 3);             // divergent -> VMEM load
    #pragma unroll
    for (int k = 0; k < DPTH; ++k) {
        const int r = (w == 0) ? (1 + k) : (TT - 2 - k);
        const float* rp = gLb + (size_t)r * GSTR;
        pf[k]  = *(const float4*)(rp + 4 * lane);
        pbf[k] = rp[bofs];
    }

    if (w == 0) {
        const float* gs = gLb + (size_t)(1 + DPTH) * GSTR;   // next row to stage
        for (int c = 0; c < NCH; ++c) {
            #pragma unroll
            for (int k = 0; k < DPTH; ++k) {
                const float4 c4 = pf[k];
                const float  cb = pbf[k];
                pf[k]  = *(const float4*)(gs + 4 * lane);
                pbf[k] = gs[bofs];
                gs += GSTR;
                __builtin_amdgcn_sched_barrier(0);
                fwd_step(cb, c4.x, c4.y, c4.z, c4.w);
                if (k == 3 || k == 7) renorm();
            }
        }
        #pragma unroll
        for (int k = 0; k < 7; ++k) {              // tail t = 1017..1023
            fwd_step(pbf[k], pf[k].x, pf[k].y, pf[k].z, pf[k].w);
            if (k == 3) renorm();
        }
    } else {
        const float* gs = gLb + (size_t)(TT - 2 - DPTH) * GSTR;
        for (int c = 0; c < NCH; ++c) {
            #pragma unroll
            for (int k = 0; k < DPTH; ++k) {
                const float4 c4 = pf[k];
                const float  cb = pbf[k];
                pf[k]  = *(const float4*)(gs + 4 * lane);
                pbf[k] = gs[bofs];
                gs -= GSTR;
                __builtin_amdgcn_sched_barrier(0);
                bwd_step(cb, c4.x, c4.y, c4.z, c4.w);
                if (k == 3 || k == 7) renorm();
            }
        }
        #pragma unroll
        for (int k = 0; k < 7; ++k) {              // rows 1030..1024
            bwd_step(pbf[k], pf[k].x, pf[k].y, pf[k].z, pf[k].w);
            if (k == 3) renorm();
        }

        // combo: beta[TM][s] = g[s] + g[s+1] + allow2[s+2]*g[s+2] (no p mult)
        float d1 = __shfl_down(f[1], 1);
        int   de = __shfl_down(e, 1);
        if (lane == 63) { d1 = 0.0f; de = e; }
        int dlt = de - e;
        if (dlt >= RBTH) {                         // one-shot, per-lane safe
            #pragma unroll
            for (int j = 0; j < 9; ++j) f[j] = LDEXP(f[j], -dlt);
            e = de; dlt = 0;
        }
        const float bf = LDEXP(d1, dlt);
        float cb[9];
        cb[0] = f[0] + f[1];
        cb[1] = f[1] + f[2] + f[3] * kdn[0];
        cb[2] = f[2] + f[3];
        cb[3] = f[3] + f[4] + f[5] * kdn[1];
        cb[4] = f[4] + f[5];
        cb[5] = f[5] + f[6] + f[7] * kdn[2];
        cb[6] = f[6] + f[7];
        cb[7] = f[7] + f[8] + bf   * kdn[3];
        cb[8] = f[8] + bf;                          // combo[512] (lane 63: bf=0)

        #pragma unroll
        for (int j = 0; j < 8; ++j) cw[8 * lane + j] = cb[j];
        if (lane == 63) cw[512] = cb[8];
        ew[lane] = e;
    }

    __syncthreads();

    if (w == 0) {
        // lane l's 8 cells align exactly with bwd lane l's 8 cells
        float part = 0.0f;
        #pragma unroll
        for (int j = 0; j < 8; ++j) part += f[j] * cw[8 * lane + j];
        if (lane == 63) part += f[8] * cw[512];
        int   ep = (part > 0.0f) ? (e + ew[lane]) : EMINI;
        float m  = part;
        #pragma unroll
        for (int d = 1; d < 64; d <<= 1) {
            const float mo = __shfl_xor(m, d);
            const int   eo = __shfl_xor(ep, d);
            const int   E  = ep > eo ? ep : eo;
            m  = LDEXP(m, ep - E) + LDEXP(mo, eo - E);
            ep = E;
        }
        if (lane == 0)
            out[b] = -LN2F * ((float)ep + __builtin_amdgcn_logf(m));
    }
}

// ---------------------------------------------------------------------------
// Fallback (round-6 verbatim, proven): used only if ws_size is too small.
// ---------------------------------------------------------------------------
__launch_bounds__(128, 1)
__global__ void ctc_fb_kernel(const int* __restrict__ y_true,
                              const float* __restrict__ y_pred,
                              float* __restrict__ out)
{
    __shared__ float cw[SS];
    __shared__ int   ew[64];

    const int tid   = threadIdx.x;
    const int w     = tid >> 6;
    const int lane  = tid & 63;
    const int b     = blockIdx.x;
    const int blank = CC - 1;

    const int*   lab  = y_true + b * LL;
    const float* base = y_pred + (size_t)b * TT * CC;

    int   col[4];
    float kup[4], kdn[4];
    #pragma unroll
    for (int i = 0; i < 4; ++i) {
        const int li = 4 * lane + i;
        const int z  = lab[li];
        col[i] = z;
        const int zm = (li >= 1) ? lab[li - 1] : -1;
        kup[i] = (z != zm) ? 1.0f : 0.0f;
        kdn[i] = (li <= 254 && lab[li + 1] != z) ? 1.0f : 0.0f;
    }

    float f[9];
    #pragma unroll
    for (int j = 0; j < 9; ++j) f[j] = 0.0f;
    int  e = 0;
    bool lzero;

    if (w == 0) {
        if (lane == 0) { f[0] = base[blank] + EPSF; f[1] = base[col[0]] + EPSF; }
        lzero = (lane != 0);
    } else {
        if (lane == 63) {
            const float* rT = base + (size_t)(TT - 1) * CC;
            f[7] = rT[col[3]] + EPSF; f[8] = rT[blank] + EPSF;
        }
        lzero = (lane != 63);
    }

    float pfb[DPTH]; float pfl[DPTH][4];
    #pragma unroll
    for (int k = 0; k < DPTH; ++k) {
        const int r = (w == 0) ? (1 + k) : (TT - 2 - k);
        const float* rp = base + (size_t)r * CC;
        pfb[k] = rp[blank];
        #pragma unroll
        for (int i = 0; i < 4; ++i) pfl[k][i] = rp[col[i]];
    }

    auto renorm = [&]() {
        float m = fmaxf(fmaxf(fmaxf(f[0], f[1]), fmaxf(f[2], f[3])),
                        fmaxf(fmaxf(f[4], f[5]), fmaxf(f[6], fmaxf(f[7], f[8]))));
        const int em = FREXP_EXP(m);
        #pragma unroll
        for (int j = 0; j < 9; ++j) f[j] = LDEXP(f[j], -em);
        e += em;
    };
    auto fwd_step = [&](float pb, float p0, float p1, float p2, float p3) {
        float u7 = __shfl_up(f[7], 1);
        int   ue = __shfl_up(e, 1);
        if (lane == 0) { u7 = 0.0f; ue = e; }
        int dlt = ue - e;
        const bool rb = lzero || (dlt >= RBTH);
        if (__ballot(rb)) {
            const int sh = rb ? -dlt : 0;
            #pragma unroll
            for (int j = 0; j < 9; ++j) f[j] = LDEXP(f[j], sh);
            e = rb ? ue : e; dlt = rb ? 0 : dlt;
            lzero = lzero && (u7 == 0.0f);
        }
        const float bf = LDEXP(u7, dlt);
        const float n0 = (f[0] + bf) * pb;
        const float n1 = (f[1] + f[0] + bf   * kup[0]) * p0;
        const float n2 = (f[2] + f[1]) * pb;
        const float n3 = (f[3] + f[2] + f[1] * kup[1]) * p1;
        const float n4 = (f[4] + f[3]) * pb;
        const float n5 = (f[5] + f[4] + f[3] * kup[2]) * p2;
        const float n6 = (f[6] + f[5]) * pb;
        const float n7 = (f[7] + f[6] + f[5] * kup[3]) * p3;
        const float n8 = (f[8] + f[7]) * pb;
        f[0]=n0; f[1]=n1; f[2]=n2; f[3]=n3; f[4]=n4;
        f[5]=n5; f[6]=n6; f[7]=n7; f[8]=n8;
    };
    auto bwd_step = [&](float pb, float p0, float p1, float p2, float p3) {
        float d1 = __shfl_down(f[1], 1);
        int   de = __shfl_down(e, 1);
        if (lane == 63) { d1 = 0.0f; de = e; }
        int dlt = de - e;
        const bool rb = lzero || (dlt >= RBTH);
        if (__ballot(rb)) {
            const int sh = rb ? -dlt : 0;
            #pragma unroll
            for (int j = 0; j < 9; ++j) f[j] = LDEXP(f[j], sh);
            e = rb ? de : e; dlt = rb ? 0 : dlt;
            lzero = lzero && (d1 == 0.0f);
        }
        const float bf = LDEXP(d1, dlt);
        const float n0 = (f[0] + f[1]) * pb;
        const float n1 = (f[1] + f[2] + f[3] * kdn[0]) * p0;
        const float n2 = (f[2] + f[3]) * pb;
        const float n3 = (f[3] + f[4] + f[5] * kdn[1]) * p1;
        const float n4 = (f[4] + f[5]) * pb;
        const float n5 = (f[5] + f[6] + f[7] * kdn[2]) * p2;
        const float n6 = (f[6] + f[7]) * pb;
        const float n7 = (f[7] + f[8] + bf   * kdn[3]) * p3;
        const float n8 = (f[8] + bf) * pb;
        f[0]=n0; f[1]=n1; f[2]=n2; f[3]=n3; f[4]=n4;
        f[5]=n5; f[6]=n6; f[7]=n7; f[8]=n8;
    };

    if (w == 0) {
        for (int c = 0; c < NCH; ++c) {
            #pragma unroll
            for (int k = 0; k < DPTH; ++k) {
                const float pb = pfb[k] + EPSF;
                const float p0 = pfl[k][0] + EPSF, p1 = pfl[k][1] + EPSF;
                const float p2 = pfl[k][2] + EPSF, p3 = pfl[k][3] + EPSF;
                int tp = 1 + c * DPTH + k + DPTH; if (tp > TM) tp = TM;
                const float* rp = base + (size_t)tp * CC;
                pfb[k] = rp[blank];
                #pragma unroll
                for (int i = 0; i < 4; ++i) pfl[k][i] = rp[col[i]];
                fwd_step(pb, p0, p1, p2, p3);
                if (k == 3 || k == 7) renorm();
            }
        }
        #pragma unroll
        for (int k = 0; k < 7; ++k) {
            fwd_step(pfb[k] + EPSF, pfl[k][0] + EPSF, pfl[k][1] + EPSF,
                     pfl[k][2] + EPSF, pfl[k][3] + EPSF);
            if (k == 3) renorm();
        }
    } else {
        for (int c = 0; c < NCH; ++c) {
            #pragma unroll
            for (int k = 0; k < DPTH; ++k) {
                const float pb = pfb[k] + EPSF;
                const float p0 = pfl[k][0] + EPSF, p1 = pfl[k][1] + EPSF;
                const float p2 = pfl[k][2] + EPSF, p3 = pfl[k][3] + EPSF;
                int tp = (TT - 2) - (c * DPTH + k) - DPTH; if (tp < TM + 1) tp = TM + 1;
                const float* rp = base + (size_t)tp * CC;
                pfb[k] = rp[blank];
                #pragma unroll
                for (int i = 0; i < 4; ++i) pfl[k][i] = rp[col[i]];
                bwd_step(pb, p0, p1, p2, p3);
                if (k == 3 || k == 7) renorm();
            }
        }
        #pragma unroll
        for (int k = 0; k < 7; ++k) {
            bwd_step(pfb[k] + EPSF, pfl[k][0] + EPSF, pfl[k][1] + EPSF,
                     pfl[k][2] + EPSF, pfl[k][3] + EPSF);
            if (k == 3) renorm();
        }

        float d1 = __shfl_down(f[1], 1);
        int   de = __shfl_down(e, 1);
        if (lane == 63) { d1 = 0.0f; de = e; }
        int dlt = de - e;
        if (dlt >= RBTH) {
            #pragma unroll
            for (int j = 0; j < 9; ++j) f[j] = LDEXP(f[j], -dlt);
            e = de; dlt = 0;
        }
        const float bf = LDEXP(d1, dlt);
        float cb[9];
        cb[0] = f[0] + f[1];
        cb[1] = f[1] + f[2] + f[3] * kdn[0];
        cb[2] = f[2] + f[3];
        cb[3] = f[3] + f[4] + f[5] * kdn[1];
        cb[4] = f[4] + f[5];
        cb[5] = f[5] + f[6] + f[7] * kdn[2];
        cb[6] = f[6] + f[7];
        cb[7] = f[7] + f[8] + bf   * kdn[3];
        cb[8] = f[8] + bf;
        #pragma unroll
        for (int j = 0; j < 8; ++j) cw[8 * lane + j] = cb[j];
        if (lane == 63) cw[512] = cb[8];
        ew[lane] = e;
    }

    __syncthreads();

    if (w == 0) {
        float part = 0.0f;
        #pragma unroll
        for (int j = 0; j < 8; ++j) part += f[j] * cw[8 * lane + j];
        if (lane == 63) part += f[8] * cw[512];
        int   ep = (part > 0.0f) ? (e + ew[lane]) : EMINI;
        float m  = part;
        #pragma unroll
        for (int d = 1; d < 64; d <<= 1) {
            const float mo = __shfl_xor(m, d);
            const int   eo = __shfl_xor(ep, d);
            const int   E  = ep > eo ? ep : eo;
            m  = LDEXP(m, ep - E) + LDEXP(mo, eo - E);
            ep = E;
        }
        if (lane == 0)
            out[b] = -LN2F * ((float)ep + __builtin_amdgcn_logf(m));
    }
}

extern "C" void kernel_launch(void* const* d_in, const int* in_sizes, int n_in,
                              void* d_out, int out_size, void* d_ws, size_t ws_size,
                              hipStream_t stream)
{
    const int*   y_true = (const int*)d_in[0];
    const float* y_pred = (const float*)d_in[1];
    float*       out    = (float*)d_out;
    const int B = in_sizes[0] / LL;   // 32

    const size_t need = (size_t)B * TT * GSTR * sizeof(float);  // ~68.2 MB
    if (ws_size >= need) {
        float* gat = (float*)d_ws;
        ctc_gather_kernel<<<dim3(B, 32), 256, 0, stream>>>(y_true, y_pred, gat);
        ctc_fast_kernel<<<B, 128, 0, stream>>>(y_true, y_pred, gat, out);
    } else {
        ctc_fb_kernel<<<B, 128, 0, stream>>>(y_true, y_pred, out);
    }
}

// Round 13
// 175.441 us; speedup vs baseline: 1.8139x; 1.2035x over previous
//
#include <hip/hip_runtime.h>

#define TT   2048
#define CC   256
#define LL   256
#define SS   513            // 2*LL+1
#define TM   1023           // meet point: fwd -> alpha[TM], bwd -> gamma[TM+1]
#define EPSF (1e-7f)
#define LN2F (0.69314718055994531f)
#define DPTH 8              // fallback prefetch depth
#define RBTH 64
#define NCH  127
#define EMINI (-2000000000)
#define GSTR 260            // gat row stride: 256 labels + 4x blank replicas

#if __has_builtin(__builtin_amdgcn_frexp_expf)
#define FREXP_EXP __builtin_amdgcn_frexp_expf
#else
static __device__ __forceinline__ int FREXP_EXP(float x){ int e; return (frexpf(x,&e), e); }
#endif
#if __has_builtin(__builtin_amdgcn_ldexpf)
#define LDEXP __builtin_amdgcn_ldexpf
#else
#define LDEXP ldexpf
#endif

// ---------------------------------------------------------------------------
// Pass 1 (R12 verbatim, proven): compact gather.
//   gat[b][t][i]     = y_pred[b][t][lab[i]] + eps   (i = 0..255)
//   gat[b][t][256+j] = y_pred[b][t][blank]  + eps   (j = 0..3, replicas)
// ---------------------------------------------------------------------------
__launch_bounds__(256, 4)
__global__ void ctc_gather_kernel(const int* __restrict__ y_true,
                                  const float* __restrict__ y_pred,
                                  float* __restrict__ gat)
{
    const int b   = blockIdx.x;
    const int i   = threadIdx.x;                 // 0..255
    const int col = y_true[b * LL + i];
    const float* rp = y_pred + (size_t)b * TT * CC;
    float*       gp = gat    + (size_t)b * TT * GSTR;
    const int tch = TT / gridDim.y;
    const int t0  = blockIdx.y * tch;
    #pragma unroll 4
    for (int t = t0; t < t0 + tch; ++t) {
        gp[(size_t)t * GSTR + i] = rp[(size_t)t * CC + col] + EPSF;
        if (i < 4)
            gp[(size_t)t * GSTR + 256 + i] = rp[(size_t)t * CC + (CC - 1)] + EPSF;
    }
}

// ---------------------------------------------------------------------------
// Grouped DP step engines (R8-verified math, register pv).
// Window g[17]: fwd g[0..7]=prev-lane halo, g[8..16]=own f[0..8];
//              bwd g[0..8]=own, g[9..16]=next-lane halo.
// pv[8] per sweep: fwd {prev4, own4}, bwd {own4, next4}; blank separate.
// ---------------------------------------------------------------------------
template<int NSTEP>
__device__ __forceinline__ void fwd_group(float (&f)[9], int &e, bool &mm,
        const float (&kk)[8], int lane,
        float4 o0, float4 o1, float4 o2, float4 o3,
        float4 q0, float4 q1, float4 q2, float4 q3,
        float b0, float b1, float b2, float b3)
{
    float h[8];
    #pragma unroll
    for (int j = 0; j < 8; ++j) h[j] = __shfl_up(f[j], 1);
    int he = __shfl_up(e, 1);
    if (lane == 0) {
        he = e;
        #pragma unroll
        for (int j = 0; j < 8; ++j) h[j] = 0.0f;
    }
    const int E  = mm ? (e > he ? e : he) : he;
    const int dh = he - E, dn = e - E;
    float g[17];
    #pragma unroll
    for (int j = 0; j < 8; ++j) g[j] = LDEXP(h[j], dh);
    #pragma unroll
    for (int j = 0; j < 9; ++j) g[8 + j] = LDEXP(f[j], dn);
    e = E;

#define FSW(Q, O, B, LO) do {                                                 \
        const float pv[8] = {Q.x,Q.y,Q.z,Q.w,O.x,O.y,O.z,O.w};                \
        _Pragma("unroll")                                                     \
        for (int i = 16; i >= (LO); --i) {                                    \
            if (i & 1) g[i] = (g[i] + g[i-1] + g[i-2]*kk[(i-1)>>1])           \
                              * pv[(i-1)>>1];                                 \
            else       g[i] = (g[i] + g[i-1]) * (B);                          \
        }                                                                     \
    } while (0)

    if (NSTEP == 4) {
        FSW(q0,o0,b0,2); FSW(q1,o1,b1,4); FSW(q2,o2,b2,6); FSW(q3,o3,b3,8);
    } else {
        FSW(q0,o0,b0,4); FSW(q1,o1,b1,6); FSW(q2,o2,b2,8);
    }
#undef FSW

    #pragma unroll
    for (int j = 0; j < 9; ++j) f[j] = g[8 + j];
    float mx = f[0];
    #pragma unroll
    for (int j = 1; j < 9; ++j) mx = fmaxf(mx, f[j]);
    const int em = FREXP_EXP(mx);
    #pragma unroll
    for (int j = 0; j < 9; ++j) f[j] = LDEXP(f[j], -em);
    e += em;
    mm = (mx > 0.0f);
}

template<int NSTEP>
__device__ __forceinline__ void bwd_group(float (&f)[9], int &e, bool &mm,
        const float (&kk)[8], int lane,
        float4 o0, float4 o1, float4 o2, float4 o3,
        float4 q0, float4 q1, float4 q2, float4 q3,
        float b0, float b1, float b2, float b3)
{
    float h[8];
    #pragma unroll
    for (int j = 0; j < 8; ++j) h[j] = __shfl_down(f[j + 1], 1);
    int he = __shfl_down(e, 1);
    if (lane == 63) {
        he = e;
        #pragma unroll
        for (int j = 0; j < 8; ++j) h[j] = 0.0f;
    }
    const int E  = mm ? (e > he ? e : he) : he;
    const int dh = he - E, dn = e - E;
    float g[17];
    #pragma unroll
    for (int j = 0; j < 9; ++j) g[j] = LDEXP(f[j], dn);
    #pragma unroll
    for (int j = 0; j < 8; ++j) g[9 + j] = LDEXP(h[j], dh);
    e = E;

#define BSW(O, Q, B, HI) do {                                                 \
        const float pv[8] = {O.x,O.y,O.z,O.w,Q.x,Q.y,Q.z,Q.w};                \
        _Pragma("unroll")                                                     \
        for (int i = 0; i <= (HI); ++i) {                                     \
            if (i & 1) g[i] = (g[i] + g[i+1] + g[i+2]*kk[(i-1)>>1])           \
                              * pv[(i-1)>>1];                                 \
            else       g[i] = (g[i] + g[i+1]) * (B);                          \
        }                                                                     \
    } while (0)

    if (NSTEP == 4) {
        BSW(o0,q0,b0,14); BSW(o1,q1,b1,12); BSW(o2,q2,b2,10); BSW(o3,q3,b3,8);
    } else {
        BSW(o0,q0,b0,12); BSW(o1,q1,b1,10); BSW(o2,q2,b2,8);
    }
#undef BSW

    #pragma unroll
    for (int j = 0; j < 9; ++j) f[j] = g[j];
    float mx = f[0];
    #pragma unroll
    for (int j = 1; j < 9; ++j) mx = fmaxf(mx, f[j]);
    const int em = FREXP_EXP(mx);
    #pragma unroll
    for (int j = 0; j < 9; ++j) f[j] = LDEXP(f[j], -em);
    e += em;
    mm = (mx > 0.0f);
}

// ---------------------------------------------------------------------------
// Pass 2: grouped meet-in-the-middle DP. Block = 128 threads (2 waves).
//   wave 0: forward alpha, rows 1..TM; wave 1: backward gamma, rows 2046..1024.
// 255 full groups of 4 steps + 3-step tail = 1023 steps/wave. Per group:
// one batched 9-shfl exchange, 12 coalesced VMEM loads (2 float4 + blank
// per step), 4 lane-local 17-cell sweeps, one renorm. Double-buffered
// group slots -> ~2 groups of VM slack. Main-loop lgkm = shfls only.
// ---------------------------------------------------------------------------
__launch_bounds__(128, 1)
__global__ void ctc_grp_kernel(const int* __restrict__ y_true,
                               const float* __restrict__ y_pred,
                               const float* __restrict__ gat,
                               float* __restrict__ out)
{
    __shared__ float cw[SS];
    __shared__ int   ew[64];

    const int tid   = threadIdx.x;
    const int w     = tid >> 6;          // 0 = fwd, 1 = bwd
    const int lane  = tid & 63;
    const int b     = blockIdx.x;
    const int blank = CC - 1;

    const int*   lab  = y_true + b * LL;
    const float* base = y_pred + (size_t)b * TT * CC;
    const float* gLb  = gat    + (size_t)b * TT * GSTR;

    // kk[8]: fwd = allow2 into window cells (labels 4l-4..4l+3);
    //        bwd = allow2 out of window cells (labels 4l..4l+7)
    float kk[8];
    if (w == 0) {
        #pragma unroll
        for (int j = 0; j < 8; ++j) {
            const int li  = 4 * lane - 4 + j;
            const int lic = li < 0 ? 0 : li;
            const int z   = lab[lic];
            const int zm  = (li >= 1) ? lab[li - 1] : -1;
            kk[j] = (li >= 0 && z != zm) ? 1.0f : 0.0f;
        }
    } else {
        #pragma unroll
        for (int j = 0; j < 8; ++j) {
            const int li  = 4 * lane + j;
            const int lic = li > 255 ? 255 : li;
            const int z   = lab[lic];
            kk[j] = (li <= 254 && lab[li + 1] != z) ? 1.0f : 0.0f;
        }
    }

    float f[9];
    #pragma unroll
    for (int j = 0; j < 9; ++j) f[j] = 0.0f;
    int  e = 0;
    bool mm;

    if (w == 0) {
        if (lane == 0) {
            f[0] = base[blank]        + EPSF;      // s=0, t=0
            f[1] = base[lab[0]]       + EPSF;      // s=1, t=0
        }
        mm = (lane == 0);
    } else {
        if (lane == 63) {
            const float* rT = base + (size_t)(TT - 1) * CC;
            f[7] = rT[lab[255]] + EPSF;            // s=511, t=TT-1
            f[8] = rT[blank]    + EPSF;            // s=512 (shadow), t=TT-1
        }
        mm = (lane == 63);
    }

    // ---- group-slot registers ----
    const int oofs = 4 * lane;
    const int qofs = (w == 0) ? (4 * lane - 4 < 0 ? 0 : 4 * lane - 4)
                              : (4 * lane + 4);
    const int bofs = 256 + (lane & 3);
    const int dstp = (w == 0) ? GSTR : -GSTR;

    float4 s0o[4], s0q[4]; float s0b[4];
    float4 s1o[4], s1q[4]; float s1b[4];

#define LOADG(SO, SQ, SB, ROWP) do {                                          \
        const float* _rp = (ROWP);                                            \
        _Pragma("unroll")                                                     \
        for (int k = 0; k < 4; ++k) {                                         \
            SO[k] = *(const float4*)(_rp + oofs);                             \
            SQ[k] = *(const float4*)(_rp + qofs);                             \
            SB[k] = _rp[bofs];                                                \
            _rp += dstp;                                                      \
        }                                                                     \
    } while (0)

    // prologue: groups 0 and 1
    const float* grow = (w == 0) ? (gLb + (size_t)1 * GSTR)
                                 : (gLb + (size_t)2046 * GSTR);
    LOADG(s0o, s0q, s0b, grow); grow += 4 * dstp;
    LOADG(s1o, s1q, s1b, grow); grow += 4 * dstp;

#define PROC(SO, SQ, SB, NS) do {                                             \
        const float4 a0 = SO[0], a1 = SO[1], a2 = SO[2], a3 = SO[3];          \
        const float4 p0 = SQ[0], p1 = SQ[1], p2 = SQ[2], p3 = SQ[3];          \
        const float  c0 = SB[0], c1 = SB[1], c2 = SB[2], c3 = SB[3];          \
        if (NS == 4) { LOADG(SO, SQ, SB, grow); grow += 4 * dstp; }           \
        __builtin_amdgcn_sched_barrier(0);                                    \
        if (w == 0) fwd_group<NS>(f, e, mm, kk, lane,                         \
                        a0,a1,a2,a3, p0,p1,p2,p3, c0,c1,c2,c3);               \
        else        bwd_group<NS>(f, e, mm, kk, lane,                         \
                        a0,a1,a2,a3, p0,p1,p2,p3, c0,c1,c2,c3);               \
    } while (0)

    // main loop: 127 iterations x 2 groups = groups 0..253
    for (int c = 0; c < 127; ++c) {
        PROC(s0o, s0q, s0b, 4);        // group 2c;   reload <- group 2c+2
        PROC(s1o, s1q, s1b, 4);        // group 2c+1; reload <- group 2c+3
    }
    // epilogue: group 254 (full, no reload needed -> loads beyond are issued
    // by PROC; rows exist in gat, never consumed) ... use non-reloading path:
    {
        const float4 a0 = s0o[0], a1 = s0o[1], a2 = s0o[2], a3 = s0o[3];
        const float4 p0 = s0q[0], p1 = s0q[1], p2 = s0q[2], p3 = s0q[3];
        const float  c0 = s0b[0], c1 = s0b[1], c2 = s0b[2], c3 = s0b[3];
        if (w == 0) fwd_group<4>(f, e, mm, kk, lane,
                        a0,a1,a2,a3, p0,p1,p2,p3, c0,c1,c2,c3);
        else        bwd_group<4>(f, e, mm, kk, lane,
                        a0,a1,a2,a3, p0,p1,p2,p3, c0,c1,c2,c3);
    }
    {   // tail: group 255, 3 steps
        const float4 a0 = s1o[0], a1 = s1o[1], a2 = s1o[2], a3 = s1o[3];
        const float4 p0 = s1q[0], p1 = s1q[1], p2 = s1q[2], p3 = s1q[3];
        const float  c0 = s1b[0], c1 = s1b[1], c2 = s1b[2], c3 = s1b[3];
        if (w == 0) fwd_group<3>(f, e, mm, kk, lane,
                        a0,a1,a2,a3, p0,p1,p2,p3, c0,c1,c2,c3);
        else        bwd_group<3>(f, e, mm, kk, lane,
                        a0,a1,a2,a3, p0,p1,p2,p3, c0,c1,c2,c3);
    }
#undef PROC
#undef LOADG

    if (w == 1) {
        // combo: beta[TM][s] = g[s] + g[s+1] + allow2[s+2]*g[s+2]
        float d1 = __shfl_down(f[1], 1);
        int   de = __shfl_down(e, 1);
        if (lane == 63) { d1 = 0.0f; de = e; }
        int dlt = de - e;
        if (dlt >= RBTH) {
            #pragma unroll
            for (int j = 0; j < 9; ++j) f[j] = LDEXP(f[j], -dlt);
            e = de; dlt = 0;
        }
        const float bf = LDEXP(d1, dlt);
        float cb[9];
        cb[0] = f[0] + f[1];
        cb[1] = f[1] + f[2] + f[3] * kk[0];
        cb[2] = f[2] + f[3];
        cb[3] = f[3] + f[4] + f[5] * kk[1];
        cb[4] = f[4] + f[5];
        cb[5] = f[5] + f[6] + f[7] * kk[2];
        cb[6] = f[6] + f[7];
        cb[7] = f[7] + f[8] + bf   * kk[3];
        cb[8] = f[8] + bf;                          // combo[512]
        #pragma unroll
        for (int j = 0; j < 8; ++j) cw[8 * lane + j] = cb[j];
        if (lane == 63) cw[512] = cb[8];
        ew[lane] = e;
    }

    __syncthreads();

    if (w == 0) {
        float part = 0.0f;
        #pragma unroll
        for (int j = 0; j < 8; ++j) part += f[j] * cw[8 * lane + j];
        if (lane == 63) part += f[8] * cw[512];
        int   ep = (part > 0.0f) ? (e + ew[lane]) : EMINI;
        float m  = part;
        #pragma unroll
        for (int d = 1; d < 64; d <<= 1) {
            const float mo = __shfl_xor(m, d);
            const int   eo = __shfl_xor(ep, d);
            const int   E  = ep > eo ? ep : eo;
            m  = LDEXP(m, ep - E) + LDEXP(mo, eo - E);
            ep = E;
        }
        if (lane == 0)
            out[b] = -LN2F * ((float)ep + __builtin_amdgcn_logf(m));
    }
}

// ---------------------------------------------------------------------------
// Fallback (round-6 verbatim, proven): used only if ws_size is too small.
// ---------------------------------------------------------------------------
__launch_bounds__(128, 1)
__global__ void ctc_fb_kernel(const int* __restrict__ y_true,
                              const float* __restrict__ y_pred,
                              float* __restrict__ out)
{
    __shared__ float cw[SS];
    __shared__ int   ew[64];

    const int tid   = threadIdx.x;
    const int w     = tid >> 6;
    const int lane  = tid & 63;
    const int b     = blockIdx.x;
    const int blank = CC - 1;

    const int*   lab  = y_true + b * LL;
    const float* base = y_pred + (size_t)b * TT * CC;

    int   col[4];
    float kup[4], kdn[4];
    #pragma unroll
    for (int i = 0; i < 4; ++i) {
        const int li = 4 * lane + i;
        const int z  = lab[li];
        col[i] = z;
        const int zm = (li >= 1) ? lab[li - 1] : -1;
        kup[i] = (z != zm) ? 1.0f : 0.0f;
        kdn[i] = (li <= 254 && lab[li + 1] != z) ? 1.0f : 0.0f;
    }

    float f[9];
    #pragma unroll
    for (int j = 0; j < 9; ++j) f[j] = 0.0f;
    int  e = 0;
    bool lzero;

    if (w == 0) {
        if (lane == 0) { f[0] = base[blank] + EPSF; f[1] = base[col[0]] + EPSF; }
        lzero = (lane != 0);
    } else {
        if (lane == 63) {
            const float* rT = base + (size_t)(TT - 1) * CC;
            f[7] = rT[col[3]] + EPSF; f[8] = rT[blank] + EPSF;
        }
        lzero = (lane != 63);
    }

    float pfb[DPTH]; float pfl[DPTH][4];
    #pragma unroll
    for (int k = 0; k < DPTH; ++k) {
        const int r = (w == 0) ? (1 + k) : (TT - 2 - k);
        const float* rp = base + (size_t)r * CC;
        pfb[k] = rp[blank];
        #pragma unroll
        for (int i = 0; i < 4; ++i) pfl[k][i] = rp[col[i]];
    }

    auto renorm = [&]() {
        float m = fmaxf(fmaxf(fmaxf(f[0], f[1]), fmaxf(f[2], f[3])),
                        fmaxf(fmaxf(f[4], f[5]), fmaxf(f[6], fmaxf(f[7], f[8]))));
        const int em = FREXP_EXP(m);
        #pragma unroll
        for (int j = 0; j < 9; ++j) f[j] = LDEXP(f[j], -em);
        e += em;
    };
    auto fwd_step = [&](float pb, float p0, float p1, float p2, float p3) {
        float u7 = __shfl_up(f[7], 1);
        int   ue = __shfl_up(e, 1);
        if (lane == 0) { u7 = 0.0f; ue = e; }
        int dlt = ue - e;
        const bool rb = lzero || (dlt >= RBTH);
        if (__ballot(rb)) {
            const int sh = rb ? -dlt : 0;
            #pragma unroll
            for (int j = 0; j < 9; ++j) f[j] = LDEXP(f[j], sh);
            e = rb ? ue : e; dlt = rb ? 0 : dlt;
            lzero = lzero && (u7 == 0.0f);
        }
        const float bf = LDEXP(u7, dlt);
        const float n0 = (f[0] + bf) * pb;
        const float n1 = (f[1] + f[0] + bf   * kup[0]) * p0;
        const float n2 = (f[2] + f[1]) * pb;
        const float n3 = (f[3] + f[2] + f[1] * kup[1]) * p1;
        const float n4 = (f[4] + f[3]) * pb;
        const float n5 = (f[5] + f[4] + f[3] * kup[2]) * p2;
        const float n6 = (f[6] + f[5]) * pb;
        const float n7 = (f[7] + f[6] + f[5] * kup[3]) * p3;
        const float n8 = (f[8] + f[7]) * pb;
        f[0]=n0; f[1]=n1; f[2]=n2; f[3]=n3; f[4]=n4;
        f[5]=n5; f[6]=n6; f[7]=n7; f[8]=n8;
    };
    auto bwd_step = [&](float pb, float p0, float p1, float p2, float p3) {
        float d1 = __shfl_down(f[1], 1);
        int   de = __shfl_down(e, 1);
        if (lane == 63) { d1 = 0.0f; de = e; }
        int dlt = de - e;
        const bool rb = lzero || (dlt >= RBTH);
        if (__ballot(rb)) {
            const int sh = rb ? -dlt : 0;
            #pragma unroll
            for (int j = 0; j < 9; ++j) f[j] = LDEXP(f[j], sh);
            e = rb ? de : e; dlt = rb ? 0 : dlt;
            lzero = lzero && (d1 == 0.0f);
        }
        const float bf = LDEXP(d1, dlt);
        const float n0 = (f[0] + f[1]) * pb;
        const float n1 = (f[1] + f[2] + f[3] * kdn[0]) * p0;
        const float n2 = (f[2] + f[3]) * pb;
        const float n3 = (f[3] + f[4] + f[5] * kdn[1]) * p1;
        const float n4 = (f[4] + f[5]) * pb;
        const float n5 = (f[5] + f[6] + f[7] * kdn[2]) * p2;
        const float n6 = (f[6] + f[7]) * pb;
        const float n7 = (f[7] + f[8] + bf   * kdn[3]) * p3;
        const float n8 = (f[8] + bf) * pb;
        f[0]=n0; f[1]=n1; f[2]=n2; f[3]=n3; f[4]=n4;
        f[5]=n5; f[6]=n6; f[7]=n7; f[8]=n8;
    };

    if (w == 0) {
        for (int c = 0; c < NCH; ++c) {
            #pragma unroll
            for (int k = 0; k < DPTH; ++k) {
                const float pb = pfb[k] + EPSF;
                const float p0 = pfl[k][0] + EPSF, p1 = pfl[k][1] + EPSF;
                const float p2 = pfl[k][2] + EPSF, p3 = pfl[k][3] + EPSF;
                int tp = 1 + c * DPTH + k + DPTH; if (tp > TM) tp = TM;
                const float* rp = base + (size_t)tp * CC;
                pfb[k] = rp[blank];
                #pragma unroll
                for (int i = 0; i < 4; ++i) pfl[k][i] = rp[col[i]];
                fwd_step(pb, p0, p1, p2, p3);
                if (k == 3 || k == 7) renorm();
            }
        }
        #pragma unroll
        for (int k = 0; k < 7; ++k) {
            fwd_step(pfb[k] + EPSF, pfl[k][0] + EPSF, pfl[k][1] + EPSF,
                     pfl[k][2] + EPSF, pfl[k][3] + EPSF);
            if (k == 3) renorm();
        }
    } else {
        for (int c = 0; c < NCH; ++c) {
            #pragma unroll
            for (int k = 0; k < DPTH; ++k) {
                const float pb = pfb[k] + EPSF;
                const float p0 = pfl[k][0] + EPSF, p1 = pfl[k][1] + EPSF;
                const float p2 = pfl[k][2] + EPSF, p3 = pfl[k][3] + EPSF;
                int tp = (TT - 2) - (c * DPTH + k) - DPTH; if (tp < TM + 1) tp = TM + 1;
                const float* rp = base + (size_t)tp * CC;
                pfb[k] = rp[blank];
                #pragma unroll
                for (int i = 0; i < 4; ++i) pfl[k][i] = rp[col[i]];
                bwd_step(pb, p0, p1, p2, p3);
                if (k == 3 || k == 7) renorm();
            }
        }
        #pragma unroll
        for (int k = 0; k < 7; ++k) {
            bwd_step(pfb[k] + EPSF, pfl[k][0] + EPSF, pfl[k][1] + EPSF,
                     pfl[k][2] + EPSF, pfl[k][3] + EPSF);
            if (k == 3) renorm();
        }

        float d1 = __shfl_down(f[1], 1);
        int   de = __shfl_down(e, 1);
        if (lane == 63) { d1 = 0.0f; de = e; }
        int dlt = de - e;
        if (dlt >= RBTH) {
            #pragma unroll
            for (int j = 0; j < 9; ++j) f[j] = LDEXP(f[j], -dlt);
            e = de; dlt = 0;
        }
        const float bf = LDEXP(d1, dlt);
        float cb[9];
        cb[0] = f[0] + f[1];
        cb[1] = f[1] + f[2] + f[3] * kdn[0];
        cb[2] = f[2] + f[3];
        cb[3] = f[3] + f[4] + f[5] * kdn[1];
        cb[4] = f[4] + f[5];
        cb[5] = f[5] + f[6] + f[7] * kdn[2];
        cb[6] = f[6] + f[7];
        cb[7] = f[7] + f[8] + bf   * kdn[3];
        cb[8] = f[8] + bf;
        #pragma unroll
        for (int j = 0; j < 8; ++j) cw[8 * lane + j] = cb[j];
        if (lane == 63) cw[512] = cb[8];
        ew[lane] = e;
    }

    __syncthreads();

    if (w == 0) {
        float part = 0.0f;
        #pragma unroll
        for (int j = 0; j < 8; ++j) part += f[j] * cw[8 * lane + j];
        if (lane == 63) part += f[8] * cw[512];
        int   ep = (part > 0.0f) ? (e + ew[lane]) : EMINI;
        float m  = part;
        #pragma unroll
        for (int d = 1; d < 64; d <<= 1) {
            const float mo = __shfl_xor(m, d);
            const int   eo = __shfl_xor(ep, d);
            const int   E  = ep > eo ? ep : eo;
            m  = LDEXP(m, ep - E) + LDEXP(mo, eo - E);
            ep = E;
        }
        if (lane == 0)
            out[b] = -LN2F * ((float)ep + __builtin_amdgcn_logf(m));
    }
}

extern "C" void kernel_launch(void* const* d_in, const int* in_sizes, int n_in,
                              void* d_out, int out_size, void* d_ws, size_t ws_size,
                              hipStream_t stream)
{
    const int*   y_true = (const int*)d_in[0];
    const float* y_pred = (const float*)d_in[1];
    float*       out    = (float*)d_out;
    const int B = in_sizes[0] / LL;   // 32

    const size_t need = (size_t)B * TT * GSTR * sizeof(float);  // ~68.2 MB
    if (ws_size >= need) {
        float* gat = (float*)d_ws;
        ctc_gather_kernel<<<dim3(B, 32), 256, 0, stream>>>(y_true, y_pred, gat);
        ctc_grp_kernel<<<B, 128, 0, stream>>>(y_true, y_pred, gat, out);
    } else {
        ctc_fb_kernel<<<B, 128, 0, stream>>>(y_true, y_pred, out);
    }
}